// Round 2
// baseline (214.263 us; speedup 1.0000x reference)
//
#include <hip/hip_runtime.h>

#define T_LEN 2048
#define DIM 2048
#define NH 16
#define HD 128
#define QKV_LD 6144   // 3*DIM

typedef __attribute__((ext_vector_type(8))) short short8;
typedef __attribute__((ext_vector_type(4))) float f32x4;
typedef __attribute__((ext_vector_type(4))) float float4v;
typedef __attribute__((ext_vector_type(4))) unsigned short ushort4v;

static __device__ __forceinline__ unsigned short f2bf(float f) {
  unsigned u = __builtin_bit_cast(unsigned, f);
  u += 0x7fffu + ((u >> 16) & 1u);   // round-to-nearest-even
  return (unsigned short)(u >> 16);
}

static __device__ __forceinline__ f32x4 mfma16(short8 a, short8 b, f32x4 c) {
  return __builtin_amdgcn_mfma_f32_16x16x32_bf16(a, b, c, 0, 0, 0);
}

#define GLDS16(SRC, DST)                                                            \
  __builtin_amdgcn_global_load_lds((__attribute__((address_space(1))) void*)(SRC),  \
                                   (__attribute__((address_space(3))) void*)(DST),  \
                                   16, 0, 0)

// ---------------------------------------------------------------- cast fp32->bf16
__global__ void cast_f32_bf16(const float* __restrict__ in,
                              unsigned short* __restrict__ out, int n4) {
  int i = blockIdx.x * blockDim.x + threadIdx.x;
  const int stride = gridDim.x * blockDim.x;
  for (; i < n4; i += stride) {
    float4v f = ((const float4v*)in)[i];
    ushort4v o;
    o.x = f2bf(f.x); o.y = f2bf(f.y); o.z = f2bf(f.z); o.w = f2bf(f.w);
    ((ushort4v*)out)[i] = o;
  }
}

// ---------------------------------------------------------------- GEMM: C = A * B^T
// A [M][K] bf16 row-major, B [N][K] bf16 row-major, C [M][N] (bf16 or f32).
// 128x128 tile, BK=64, 4 waves (each 64x64), global_load_lds staging,
// LDS rows 128B with byte ^= ((row&7)<<4) swizzle (pre-swizzled global source).
template <int OUT_BF16>
__global__ __launch_bounds__(256) void gemm_bt_128(
    const unsigned short* __restrict__ A,
    const unsigned short* __restrict__ B,
    void* __restrict__ Cv, int M, int N, int K) {
  __shared__ unsigned short As[128 * 64];
  __shared__ unsigned short Bs[128 * 64];
  const int tid = threadIdx.x;
  const int wave = tid >> 6;
  const int lane = tid & 63;
  const int l15 = lane & 15, l16 = lane >> 4;
  const int bm = blockIdx.y * 128;
  const int bn = blockIdx.x * 128;
  const int wr = wave >> 1, wc = wave & 1;

  f32x4 acc[4][4] = {};

  // staging source (element offsets within the 128x64 tile), inverse-swizzled
  int srow[4], scol[4];
#pragma unroll
  for (int i = 0; i < 4; ++i) {
    int lin = i * 4096 + tid * 16;     // byte index, linear LDS order
    int row = lin >> 7;                // 128B rows
    int cb = lin & 127;
    srow[i] = row;
    scol[i] = (cb ^ ((row & 7) << 4)) >> 1;
  }

  for (int k0 = 0; k0 < K; k0 += 64) {
#pragma unroll
    for (int i = 0; i < 4; ++i) {
      GLDS16(A + (size_t)(bm + srow[i]) * K + k0 + scol[i], As + i * 2048 + wave * 512);
      GLDS16(B + (size_t)(bn + srow[i]) * K + k0 + scol[i], Bs + i * 2048 + wave * 512);
    }
    __syncthreads();
#pragma unroll
    for (int kk = 0; kk < 2; ++kk) {
      const int cb = kk * 64 + l16 * 16;
      short8 af[4], bfr[4];
#pragma unroll
      for (int m = 0; m < 4; ++m) {
        int row = wr * 64 + m * 16 + l15;
        af[m] = *(const short8*)((const char*)As + row * 128 + (cb ^ ((row & 7) << 4)));
      }
#pragma unroll
      for (int n = 0; n < 4; ++n) {
        int row = wc * 64 + n * 16 + l15;
        bfr[n] = *(const short8*)((const char*)Bs + row * 128 + (cb ^ ((row & 7) << 4)));
      }
#pragma unroll
      for (int m = 0; m < 4; ++m)
#pragma unroll
        for (int n = 0; n < 4; ++n)
          acc[m][n] = mfma16(af[m], bfr[n], acc[m][n]);
    }
    __syncthreads();
  }

  // epilogue: C/D layout col=lane&15, row=(lane>>4)*4+j  [m89-verified]
#pragma unroll
  for (int m = 0; m < 4; ++m)
#pragma unroll
    for (int n = 0; n < 4; ++n) {
      int row = bm + wr * 64 + m * 16 + l16 * 4;
      int col = bn + wc * 64 + n * 16 + l15;
#pragma unroll
      for (int j = 0; j < 4; ++j) {
        if (OUT_BF16)
          ((unsigned short*)Cv)[(size_t)(row + j) * N + col] = f2bf(acc[m][n][j]);
        else
          ((float*)Cv)[(size_t)(row + j) * N + col] = acc[m][n][j];
      }
    }
}

// ---------------------------------------------------------------- V transpose
// qkv[s][4096 + h*128 + d] -> vt[h][d][s], 64-s tile per block, swizzled LDS.
__global__ __launch_bounds__(256) void transpose_v(
    const unsigned short* __restrict__ qkv, unsigned short* __restrict__ vt) {
  __shared__ unsigned short t[64 * 128];
  const int tid = threadIdx.x;
  const int h = blockIdx.y;
  const int s0 = blockIdx.x * 64;
#pragma unroll
  for (int i = 0; i < 4; ++i) {
    int lin = i * 2048 + tid * 8;    // element index in 64x128 tile
    int row = lin >> 7, col = lin & 127;
    char* dst = (char*)t + row * 256 + ((col * 2) ^ (((row >> 3) & 7) << 4));
    *(short8*)dst =
        *(const short8*)(qkv + (size_t)(s0 + row) * QKV_LD + 2 * DIM + h * HD + col);
  }
  __syncthreads();
#pragma unroll
  for (int i2 = 0; i2 < 4; ++i2) {
    int d = (tid >> 3) + i2 * 32;
    int sb = (tid & 7) * 8;
    short8 v;
#pragma unroll
    for (int j = 0; j < 8; ++j) {
      int s = sb + j;
      v[j] = *(const short*)((const char*)t + s * 256 + ((d * 2) ^ (((s >> 3) & 7) << 4)));
    }
    *(short8*)(vt + ((size_t)h * HD + d) * T_LEN + s0 + sb) = v;
  }
}

// ---------------------------------------------------------------- flash attention
// Block = 4 waves; wave w owns Q rows [blockIdx.x*64 + w*16, +16), head = blockIdx.y.
// KV tile = 64, DOUBLE-BUFFERED: issue stage(t+1) before compute(t), single
// barrier per iteration (T3-lite 2-phase) so global_load_lds latency hides
// under QK^T/softmax/PV. K staged [64 s][128 d], V staged transposed [128 d][64 s],
// LDS rows XOR-swizzled. Online softmax fp32, P via per-wave LDS (bf16).
__global__ __launch_bounds__(256) void attn_fwd(
    const unsigned short* __restrict__ qkv,
    const unsigned short* __restrict__ vt,
    unsigned short* __restrict__ ctx) {
  __shared__ unsigned short Ks[2][64 * 128];
  __shared__ unsigned short Vs[2][128 * 64];
  __shared__ unsigned short Ps[4 * 16 * 64];
  const int tid = threadIdx.x;
  const int wave = tid >> 6;
  const int lane = tid & 63;
  const int l15 = lane & 15, l16 = lane >> 4;
  const int h = blockIdx.y;
  const int q0 = blockIdx.x * 64 + wave * 16;
  const float SCL = 0.08838834764831845f * 1.4426950408889634f;  // 1/sqrt(128) * log2(e)

  // hoist Q fragments into registers: Q[q0+l15][kk*32 + l16*8 .. +7]
  short8 qf[4];
#pragma unroll
  for (int kk = 0; kk < 4; ++kk)
    qf[kk] = *(const short8*)(qkv + (size_t)(q0 + l15) * QKV_LD + h * HD + kk * 32 + l16 * 8);

  f32x4 acc_o[8] = {};
  float m_r[4] = {-1e30f, -1e30f, -1e30f, -1e30f};
  float l_r[4] = {0.f, 0.f, 0.f, 0.f};

  // staging source offsets (inverse-swizzled)
  int krow[4], kcol[4], vrow[4], vcol[4];
#pragma unroll
  for (int i = 0; i < 4; ++i) {
    int lin = i * 4096 + tid * 16;
    int r = lin >> 8;                       // K tile: 256B rows
    int cb = lin & 255;
    krow[i] = r; kcol[i] = (cb ^ ((r & 7) << 4)) >> 1;
    r = lin >> 7;                           // V tile: 128B rows
    cb = lin & 127;
    vrow[i] = r; vcol[i] = (cb ^ ((r & 7) << 4)) >> 1;
  }
  const unsigned short* kbase = qkv + 2048 + h * HD;       // K block of qkv
  const unsigned short* vbase = vt + (size_t)h * HD * T_LEN;

#define STAGE_KV(BUF, S0)                                                              \
  do {                                                                                 \
    _Pragma("unroll")                                                                  \
    for (int i = 0; i < 4; ++i) {                                                      \
      GLDS16(kbase + (size_t)((S0) + krow[i]) * QKV_LD + kcol[i],                      \
             Ks[BUF] + i * 2048 + wave * 512);                                         \
      GLDS16(vbase + (size_t)vrow[i] * T_LEN + (S0) + vcol[i],                         \
             Vs[BUF] + i * 2048 + wave * 512);                                         \
    }                                                                                  \
  } while (0)

  // prologue: stage tile 0
  STAGE_KV(0, 0);
  __syncthreads();

  const int NT = T_LEN / 64;
  int cur = 0;
  for (int t = 0; t < NT; ++t) {
    // issue next tile's staging BEFORE compute — latency hides under compute,
    // and the compiler's vmcnt(0) drain at the end-of-iter barrier is ~free.
    if (t + 1 < NT) STAGE_KV(cur ^ 1, (t + 1) * 64);

    const unsigned short* ks = Ks[cur];
    const unsigned short* vs = Vs[cur];

    // S = Q K^T  (16x64 per wave)
    f32x4 sc[4] = {};
#pragma unroll
    for (int c = 0; c < 4; ++c) {
#pragma unroll
      for (int kk = 0; kk < 4; ++kk) {
        int row = c * 16 + l15;
        int cb = kk * 64 + l16 * 16;
        short8 kf = *(const short8*)((const char*)ks + row * 256 + (cb ^ ((row & 7) << 4)));
        sc[c] = mfma16(qf[kk], kf, sc[c]);
      }
    }

    // online softmax: reduce over s = 4 frags x 16 lanes (same l16 group)
    float tmax[4], tsum[4], corr[4], p[4][4];
#pragma unroll
    for (int j = 0; j < 4; ++j)
      tmax[j] = fmaxf(fmaxf(sc[0][j], sc[1][j]), fmaxf(sc[2][j], sc[3][j])) * SCL;
#pragma unroll
    for (int mask = 1; mask < 16; mask <<= 1)
#pragma unroll
      for (int j = 0; j < 4; ++j)
        tmax[j] = fmaxf(tmax[j], __shfl_xor(tmax[j], mask));
#pragma unroll
    for (int j = 0; j < 4; ++j) {
      float nm = fmaxf(m_r[j], tmax[j]);
      corr[j] = __builtin_amdgcn_exp2f(m_r[j] - nm);
      m_r[j] = nm;
    }
#pragma unroll
    for (int c = 0; c < 4; ++c)
#pragma unroll
      for (int j = 0; j < 4; ++j)
        p[c][j] = __builtin_amdgcn_exp2f(sc[c][j] * SCL - m_r[j]);
#pragma unroll
    for (int j = 0; j < 4; ++j)
      tsum[j] = (p[0][j] + p[1][j]) + (p[2][j] + p[3][j]);
#pragma unroll
    for (int mask = 1; mask < 16; mask <<= 1)
#pragma unroll
      for (int j = 0; j < 4; ++j)
        tsum[j] += __shfl_xor(tsum[j], mask);
#pragma unroll
    for (int j = 0; j < 4; ++j)
      l_r[j] = l_r[j] * corr[j] + tsum[j];
#pragma unroll
    for (int d = 0; d < 8; ++d)
#pragma unroll
      for (int j = 0; j < 4; ++j)
        acc_o[d][j] *= corr[j];

    // P -> per-wave LDS (bf16, swizzled rows of 128B)
    char* pbase = (char*)Ps + wave * 2048;
#pragma unroll
    for (int c = 0; c < 4; ++c)
#pragma unroll
      for (int j = 0; j < 4; ++j) {
        int q = l16 * 4 + j;
        int s = c * 16 + l15;
        *(unsigned short*)(pbase + q * 128 + ((s * 2) ^ ((q & 7) << 4))) = f2bf(p[c][j]);
      }

    // ctx += P @ V  (A = P from LDS, B = V from transposed Vs)
#pragma unroll
    for (int kk = 0; kk < 2; ++kk) {
      int cb = kk * 64 + l16 * 16;
      short8 pa = *(const short8*)(pbase + l15 * 128 + (cb ^ ((l15 & 7) << 4)));
#pragma unroll
      for (int d = 0; d < 8; ++d) {
        int row = d * 16 + l15;
        short8 vb = *(const short8*)((const char*)vs + row * 128 + (cb ^ ((row & 7) << 4)));
        acc_o[d] = mfma16(pa, vb, acc_o[d]);
      }
    }

    __syncthreads();   // next-tile staging drained; Ps/K/V safe to reuse
    cur ^= 1;
  }
#undef STAGE_KV

  // epilogue: ctx[q][h*128+d] = acc/l
  float rl[4];
#pragma unroll
  for (int j = 0; j < 4; ++j) rl[j] = 1.0f / l_r[j];
#pragma unroll
  for (int d = 0; d < 8; ++d)
#pragma unroll
    for (int j = 0; j < 4; ++j) {
      int row = q0 + l16 * 4 + j;
      int col = h * HD + d * 16 + l15;
      ctx[(size_t)row * DIM + col] = f2bf(acc_o[d][j] * rl[j]);
    }
}

// ---------------------------------------------------------------- launcher
extern "C" void kernel_launch(void* const* d_in, const int* in_sizes, int n_in,
                              void* d_out, int out_size, void* d_ws, size_t ws_size,
                              hipStream_t stream) {
  const float* x = (const float*)d_in[0];
  const float* w_in = (const float*)d_in[1];
  const float* w_out = (const float*)d_in[2];

  char* ws = (char*)d_ws;
  unsigned short* xbf  = (unsigned short*)(ws + 0);          //  8 MB
  unsigned short* wibf = (unsigned short*)(ws + 8388608);    // 24 MB
  unsigned short* wobf = (unsigned short*)(ws + 33554432);   //  8 MB
  unsigned short* qkv  = (unsigned short*)(ws + 41943040);   // 24 MB
  unsigned short* ctx  = (unsigned short*)(ws + 67108864);   //  8 MB
  unsigned short* vt   = (unsigned short*)(ws + 75497472);   //  8 MB  (end: 80 MB)

  cast_f32_bf16<<<2048, 256, 0, stream>>>(x, xbf, (T_LEN * DIM) / 4);
  cast_f32_bf16<<<2048, 256, 0, stream>>>(w_in, wibf, (3 * DIM * DIM) / 4);
  cast_f32_bf16<<<2048, 256, 0, stream>>>(w_out, wobf, (DIM * DIM) / 4);

  // qkv = x @ w_in^T   [2048 x 6144]
  gemm_bt_128<1><<<dim3(48, 16), 256, 0, stream>>>(xbf, wibf, (void*)qkv, T_LEN, 3 * DIM, DIM);
  // vt[h][d][s] = V
  transpose_v<<<dim3(32, 16), 256, 0, stream>>>(qkv, vt);
  // attention -> ctx [2048 x 2048] bf16
  attn_fwd<<<dim3(32, 16), 256, 0, stream>>>(qkv, vt, ctx);
  // out = ctx @ w_out^T  (fp32)
  gemm_bt_128<0><<<dim3(16, 16), 256, 0, stream>>>(ctx, wobf, d_out, T_LEN, DIM, DIM);
}

// Round 3
// 189.800 us; speedup vs baseline: 1.1289x; 1.1289x over previous
//
#include <hip/hip_runtime.h>

#define T_LEN 2048
#define DIM 2048
#define NH 16
#define HD 128
#define QKV_LD 6144   // 3*DIM

typedef __attribute__((ext_vector_type(8))) short short8;
typedef __attribute__((ext_vector_type(4))) float f32x4;
typedef __attribute__((ext_vector_type(4))) float float4v;
typedef __attribute__((ext_vector_type(4))) unsigned short ushort4v;
typedef __attribute__((ext_vector_type(2))) unsigned int uint2v;

static __device__ __forceinline__ unsigned short f2bf(float f) {
  unsigned u = __builtin_bit_cast(unsigned, f);
  u += 0x7fffu + ((u >> 16) & 1u);   // round-to-nearest-even
  return (unsigned short)(u >> 16);
}

static __device__ __forceinline__ f32x4 mfma16(short8 a, short8 b, f32x4 c) {
  return __builtin_amdgcn_mfma_f32_16x16x32_bf16(a, b, c, 0, 0, 0);
}

#define GLDS16(SRC, DST)                                                            \
  __builtin_amdgcn_global_load_lds((__attribute__((address_space(1))) void*)(SRC),  \
                                   (__attribute__((address_space(3))) void*)(DST),  \
                                   16, 0, 0)

// ---------------------------------------------------------------- cast fp32->bf16
__global__ void cast_f32_bf16(const float* __restrict__ in,
                              unsigned short* __restrict__ out, int n4) {
  int i = blockIdx.x * blockDim.x + threadIdx.x;
  const int stride = gridDim.x * blockDim.x;
  for (; i < n4; i += stride) {
    float4v f = ((const float4v*)in)[i];
    ushort4v o;
    o.x = f2bf(f.x); o.y = f2bf(f.y); o.z = f2bf(f.z); o.w = f2bf(f.w);
    ((ushort4v*)out)[i] = o;
  }
}

// ---------------------------------------------------------------- GEMM: C = A * B^T
// A [M][K] bf16 row-major, B [N][K] bf16 row-major, C [M][N] (bf16 or f32).
// 128x128 tile, BK=64, 4 waves (each 64x64), global_load_lds staging,
// LDS rows 128B with byte ^= ((row&7)<<4) swizzle (pre-swizzled global source).
template <int OUT_BF16>
__global__ __launch_bounds__(256) void gemm_bt_128(
    const unsigned short* __restrict__ A,
    const unsigned short* __restrict__ B,
    void* __restrict__ Cv, int M, int N, int K) {
  __shared__ unsigned short As[128 * 64];
  __shared__ unsigned short Bs[128 * 64];
  const int tid = threadIdx.x;
  const int wave = tid >> 6;
  const int lane = tid & 63;
  const int l15 = lane & 15, l16 = lane >> 4;
  const int bm = blockIdx.y * 128;
  const int bn = blockIdx.x * 128;
  const int wr = wave >> 1, wc = wave & 1;

  f32x4 acc[4][4] = {};

  // staging source (element offsets within the 128x64 tile), inverse-swizzled
  int srow[4], scol[4];
#pragma unroll
  for (int i = 0; i < 4; ++i) {
    int lin = i * 4096 + tid * 16;     // byte index, linear LDS order
    int row = lin >> 7;                // 128B rows
    int cb = lin & 127;
    srow[i] = row;
    scol[i] = (cb ^ ((row & 7) << 4)) >> 1;
  }

  for (int k0 = 0; k0 < K; k0 += 64) {
#pragma unroll
    for (int i = 0; i < 4; ++i) {
      GLDS16(A + (size_t)(bm + srow[i]) * K + k0 + scol[i], As + i * 2048 + wave * 512);
      GLDS16(B + (size_t)(bn + srow[i]) * K + k0 + scol[i], Bs + i * 2048 + wave * 512);
    }
    __syncthreads();
#pragma unroll
    for (int kk = 0; kk < 2; ++kk) {
      const int cb = kk * 64 + l16 * 16;
      short8 af[4], bfr[4];
#pragma unroll
      for (int m = 0; m < 4; ++m) {
        int row = wr * 64 + m * 16 + l15;
        af[m] = *(const short8*)((const char*)As + row * 128 + (cb ^ ((row & 7) << 4)));
      }
#pragma unroll
      for (int n = 0; n < 4; ++n) {
        int row = wc * 64 + n * 16 + l15;
        bfr[n] = *(const short8*)((const char*)Bs + row * 128 + (cb ^ ((row & 7) << 4)));
      }
#pragma unroll
      for (int m = 0; m < 4; ++m)
#pragma unroll
        for (int n = 0; n < 4; ++n)
          acc[m][n] = mfma16(af[m], bfr[n], acc[m][n]);
    }
    __syncthreads();
  }

  // epilogue: C/D layout col=lane&15, row=(lane>>4)*4+j  [m89-verified]
#pragma unroll
  for (int m = 0; m < 4; ++m)
#pragma unroll
    for (int n = 0; n < 4; ++n) {
      int row = bm + wr * 64 + m * 16 + l16 * 4;
      int col = bn + wc * 64 + n * 16 + l15;
#pragma unroll
      for (int j = 0; j < 4; ++j) {
        if (OUT_BF16)
          ((unsigned short*)Cv)[(size_t)(row + j) * N + col] = f2bf(acc[m][n][j]);
        else
          ((float*)Cv)[(size_t)(row + j) * N + col] = acc[m][n][j];
      }
    }
}

// ---------------------------------------------------------------- V transpose
// qkv[s][4096 + h*128 + d] -> vt[h][d][s], 64-s tile per block, swizzled LDS.
__global__ __launch_bounds__(256) void transpose_v(
    const unsigned short* __restrict__ qkv, unsigned short* __restrict__ vt) {
  __shared__ unsigned short t[64 * 128];
  const int tid = threadIdx.x;
  const int h = blockIdx.y;
  const int s0 = blockIdx.x * 64;
#pragma unroll
  for (int i = 0; i < 4; ++i) {
    int lin = i * 2048 + tid * 8;    // element index in 64x128 tile
    int row = lin >> 7, col = lin & 127;
    char* dst = (char*)t + row * 256 + ((col * 2) ^ (((row >> 3) & 7) << 4));
    *(short8*)dst =
        *(const short8*)(qkv + (size_t)(s0 + row) * QKV_LD + 2 * DIM + h * HD + col);
  }
  __syncthreads();
#pragma unroll
  for (int i2 = 0; i2 < 4; ++i2) {
    int d = (tid >> 3) + i2 * 32;
    int sb = (tid & 7) * 8;
    short8 v;
#pragma unroll
    for (int j = 0; j < 8; ++j) {
      int s = sb + j;
      v[j] = *(const short*)((const char*)t + s * 256 + ((d * 2) ^ (((s >> 3) & 7) << 4)));
    }
    *(short8*)(vt + ((size_t)h * HD + d) * T_LEN + s0 + sb) = v;
  }
}

// ---------------------------------------------------------------- flash attention
// Block = 4 waves; wave w owns Q rows [blockIdx.x*64 + w*16, +16), head = blockIdx.y.
// KV tile = 64, double-buffered (prefetch next tile before compute).
// SWAPPED QK^T: S^T = mfma(K,Q) so each lane (q=l15) holds 16 kv-values of one
// q-row -> softmax is in-lane reduce + 2 shfl_xor (no 4-round butterfly).
// P packed to bf16 in-register, written as 4x ds_write_b64 (swizzled, conflict-
// free). Defer-max (THR=8, log2 domain) skips the O-rescale on most tiles.
__global__ __launch_bounds__(256) void attn_fwd(
    const unsigned short* __restrict__ qkv,
    const unsigned short* __restrict__ vt,
    unsigned short* __restrict__ ctx) {
  __shared__ unsigned short Ks[2][64 * 128];
  __shared__ unsigned short Vs[2][128 * 64];
  __shared__ unsigned short Ps[4 * 16 * 64];
  const int tid = threadIdx.x;
  const int wave = tid >> 6;
  const int lane = tid & 63;
  const int l15 = lane & 15, l16 = lane >> 4;
  const int h = blockIdx.y;
  const int q0 = blockIdx.x * 64 + wave * 16;
  const float SCL = 0.08838834764831845f * 1.4426950408889634f;  // 1/sqrt(128) * log2(e)

  // hoist Q fragments into registers: Q[q0+l15][kk*32 + l16*8 .. +7]
  short8 qf[4];
#pragma unroll
  for (int kk = 0; kk < 4; ++kk)
    qf[kk] = *(const short8*)(qkv + (size_t)(q0 + l15) * QKV_LD + h * HD + kk * 32 + l16 * 8);

  f32x4 acc_o[8] = {};
  float m_r = -1e30f;   // running max (log2 domain), for q-row = l15
  float l_r = 0.f;      // running denom, for q-row = l15

  // staging source offsets (inverse-swizzled)
  int krow[4], kcol[4], vrow[4], vcol[4];
#pragma unroll
  for (int i = 0; i < 4; ++i) {
    int lin = i * 4096 + tid * 16;
    int r = lin >> 8;                       // K tile: 256B rows
    int cb = lin & 255;
    krow[i] = r; kcol[i] = (cb ^ ((r & 7) << 4)) >> 1;
    r = lin >> 7;                           // V tile: 128B rows
    cb = lin & 127;
    vrow[i] = r; vcol[i] = (cb ^ ((r & 7) << 4)) >> 1;
  }
  const unsigned short* kbase = qkv + 2048 + h * HD;       // K block of qkv
  const unsigned short* vbase = vt + (size_t)h * HD * T_LEN;

#define STAGE_KV(BUF, S0)                                                              \
  do {                                                                                 \
    _Pragma("unroll")                                                                  \
    for (int i = 0; i < 4; ++i) {                                                      \
      GLDS16(kbase + (size_t)((S0) + krow[i]) * QKV_LD + kcol[i],                      \
             Ks[BUF] + i * 2048 + wave * 512);                                         \
      GLDS16(vbase + (size_t)vrow[i] * T_LEN + (S0) + vcol[i],                         \
             Vs[BUF] + i * 2048 + wave * 512);                                         \
    }                                                                                  \
  } while (0)

  // prologue: stage tile 0
  STAGE_KV(0, 0);
  __syncthreads();

  const int NT = T_LEN / 64;
  int cur = 0;
  for (int t = 0; t < NT; ++t) {
    if (t + 1 < NT) STAGE_KV(cur ^ 1, (t + 1) * 64);

    const unsigned short* ks = Ks[cur];
    const unsigned short* vs = Vs[cur];

    // S^T = K Q^T : st[c] rows = kv (c*16 + l16*4 + j), col = q = l15
    f32x4 st[4] = {};
#pragma unroll
    for (int c = 0; c < 4; ++c) {
#pragma unroll
      for (int kk = 0; kk < 4; ++kk) {
        int row = c * 16 + l15;
        int cb = kk * 64 + l16 * 16;
        short8 kf = *(const short8*)((const char*)ks + row * 256 + (cb ^ ((row & 7) << 4)));
        st[c] = mfma16(kf, qf[kk], st[c]);   // swapped operands
      }
    }

    // ---- online softmax, lane-local for q-row l15 (replicated over l16) ----
    float pmax = -1e30f;
#pragma unroll
    for (int c = 0; c < 4; ++c)
#pragma unroll
      for (int j = 0; j < 4; ++j)
        pmax = fmaxf(pmax, st[c][j]);
    pmax *= SCL;
    pmax = fmaxf(pmax, __shfl_xor(pmax, 16));
    pmax = fmaxf(pmax, __shfl_xor(pmax, 32));

    // defer-max: only rescale when the tile max exceeds running max by >8
    // (log2 domain: P values then bounded by 2^8, fine in bf16/f32 accum)
    if (!__all(pmax - m_r <= 8.0f)) {
      float nm = fmaxf(m_r, pmax);
      float corr = __builtin_amdgcn_exp2f(m_r - nm);
      m_r = nm;
      l_r *= corr;
      float cj[4];
#pragma unroll
      for (int j = 0; j < 4; ++j) cj[j] = __shfl(corr, l16 * 4 + j);
#pragma unroll
      for (int d = 0; d < 8; ++d)
#pragma unroll
        for (int j = 0; j < 4; ++j) acc_o[d][j] *= cj[j];
    }

    float p[4][4];
    float tsum = 0.f;
#pragma unroll
    for (int c = 0; c < 4; ++c)
#pragma unroll
      for (int j = 0; j < 4; ++j) {
        p[c][j] = __builtin_amdgcn_exp2f(st[c][j] * SCL - m_r);
        tsum += p[c][j];
      }
    tsum += __shfl_xor(tsum, 16);
    tsum += __shfl_xor(tsum, 32);
    l_r += tsum;

    // ---- P -> LDS: pack bf16 pairs, 4x ds_write_b64, swizzled ----
    // layout: P[q=l15][kv], row stride 128B, byte ^= ((q&7)<<4)
    char* pbase = (char*)Ps + wave * 2048;
#pragma unroll
    for (int c = 0; c < 4; ++c) {
      uint2v w;
      w.x = (unsigned)f2bf(p[c][0]) | ((unsigned)f2bf(p[c][1]) << 16);
      w.y = (unsigned)f2bf(p[c][2]) | ((unsigned)f2bf(p[c][3]) << 16);
      int off = l15 * 128 + c * 32 + l16 * 8;
      *(uint2v*)(pbase + (off ^ ((l15 & 7) << 4))) = w;
    }

    // ---- ctx += P @ V ----
#pragma unroll
    for (int kk = 0; kk < 2; ++kk) {
      int cb = kk * 64 + l16 * 16;
      short8 pa = *(const short8*)(pbase + l15 * 128 + (cb ^ ((l15 & 7) << 4)));
#pragma unroll
      for (int d = 0; d < 8; ++d) {
        int row = d * 16 + l15;
        short8 vb = *(const short8*)((const char*)vs + row * 128 + (cb ^ ((row & 7) << 4)));
        acc_o[d] = mfma16(pa, vb, acc_o[d]);
      }
    }

    __syncthreads();   // next-tile staging drained; Ps/K/V safe to reuse
    cur ^= 1;
  }
#undef STAGE_KV

  // epilogue: ctx[q][h*128+d] = acc/l ; l_r lives at lane q=l15, acc rows are
  // q=l16*4+j -> redistribute once via shfl
  float lq[4];
#pragma unroll
  for (int j = 0; j < 4; ++j) lq[j] = 1.0f / __shfl(l_r, l16 * 4 + j);
#pragma unroll
  for (int d = 0; d < 8; ++d)
#pragma unroll
    for (int j = 0; j < 4; ++j) {
      int row = q0 + l16 * 4 + j;
      int col = h * HD + d * 16 + l15;
      ctx[(size_t)row * DIM + col] = f2bf(acc_o[d][j] * lq[j]);
    }
}

// ---------------------------------------------------------------- launcher
extern "C" void kernel_launch(void* const* d_in, const int* in_sizes, int n_in,
                              void* d_out, int out_size, void* d_ws, size_t ws_size,
                              hipStream_t stream) {
  const float* x = (const float*)d_in[0];
  const float* w_in = (const float*)d_in[1];
  const float* w_out = (const float*)d_in[2];

  char* ws = (char*)d_ws;
  unsigned short* xbf  = (unsigned short*)(ws + 0);          //  8 MB
  unsigned short* wibf = (unsigned short*)(ws + 8388608);    // 24 MB
  unsigned short* wobf = (unsigned short*)(ws + 33554432);   //  8 MB
  unsigned short* qkv  = (unsigned short*)(ws + 41943040);   // 24 MB
  unsigned short* ctx  = (unsigned short*)(ws + 67108864);   //  8 MB
  unsigned short* vt   = (unsigned short*)(ws + 75497472);   //  8 MB  (end: 80 MB)

  cast_f32_bf16<<<2048, 256, 0, stream>>>(x, xbf, (T_LEN * DIM) / 4);
  cast_f32_bf16<<<2048, 256, 0, stream>>>(w_in, wibf, (3 * DIM * DIM) / 4);
  cast_f32_bf16<<<2048, 256, 0, stream>>>(w_out, wobf, (DIM * DIM) / 4);

  // qkv = x @ w_in^T   [2048 x 6144]
  gemm_bt_128<1><<<dim3(48, 16), 256, 0, stream>>>(xbf, wibf, (void*)qkv, T_LEN, 3 * DIM, DIM);
  // vt[h][d][s] = V
  transpose_v<<<dim3(32, 16), 256, 0, stream>>>(qkv, vt);
  // attention -> ctx [2048 x 2048] bf16
  attn_fwd<<<dim3(32, 16), 256, 0, stream>>>(qkv, vt, ctx);
  // out = ctx @ w_out^T  (fp32)
  gemm_bt_128<0><<<dim3(16, 16), 256, 0, stream>>>(ctx, wobf, d_out, T_LEN, DIM, DIM);
}